// Round 4
// baseline (1245.457 us; speedup 1.0000x reference)
//
#include <hip/hip_runtime.h>

// Problem constants: B=2048, N=62 (pad 64), C_IN=512, L=3 layers, H=8, O=64.
// k_main: 256 threads/block, one batch element per block.
// Weight staging: 8 chunks of K=64, double-buffered (2x16KB) with counted-drain
// raw-barrier pipeline (T3 minimum recipe) so staging of chunk kc+1 overlaps
// the MFMA phase of chunk kc. LDS union keeps total ~35.8KB -> 4 blocks/CU.

using f32x4 = __attribute__((ext_vector_type(4))) float;
using s16x8 = __attribute__((ext_vector_type(8))) short;

__device__ __forceinline__ unsigned short f2bf(float f){
  unsigned int u = __builtin_bit_cast(unsigned int, f);
  u += 0x7fffu + ((u >> 16) & 1u);              // RNE
  return (unsigned short)(u >> 16);
}
__device__ __forceinline__ float bf2f(unsigned short h){
  unsigned int u = ((unsigned int)h) << 16;
  return __builtin_bit_cast(float, u);
}
__device__ __forceinline__ f32x4 zf4(){ f32x4 v; v[0]=0.f; v[1]=0.f; v[2]=0.f; v[3]=0.f; return v; }

__device__ __forceinline__ void async16(const void* g, void* l){
  __builtin_amdgcn_global_load_lds((const __attribute__((address_space(1))) unsigned int*)g,
                                   (__attribute__((address_space(3))) unsigned int*)l,
                                   16, 0, 0);
}

// ---------------- K0: adjacency powers, A_hat (bf16, zero-padded 64x64), d_neg ----------------
__global__ void k_prep_adj(const float* __restrict__ L,
                           unsigned short* __restrict__ ahat,  // [3][64][64] bf16
                           float* __restrict__ dneg)           // [3][64] f32
{
  __shared__ float Ls[62*62];
  __shared__ float A2s[62*62];
  const int tid = threadIdx.x;
  for (int i = tid; i < 62*62; i += 256) Ls[i] = L[i];
  __syncthreads();
  for (int i = tid; i < 62*62; i += 256){
    const int n = i / 62, m = i % 62;
    float s = 0.f;
    for (int k = 0; k < 62; ++k) s += Ls[n*62 + k] * Ls[k*62 + m];
    A2s[i] = s;
  }
  __syncthreads();
  for (int i = tid; i < 3*64*64; i += 256){
    const int l = i >> 12, r = i & 4095, n = r >> 6, m = r & 63;
    float v = 0.f;
    if (n < 62 && m < 62){
      float base = 0.f;
      if (l == 0) base = (n == m) ? 1.f : 0.f;
      else if (l == 1) base = Ls[n*62 + m];
      else base = A2s[n*62 + m];
      v = base + ((n == m) ? 1.f : 0.f);          // A_hat = A + I
    }
    ahat[i] = f2bf(v);
  }
  for (int i = tid; i < 3*64; i += 256){
    const int l = i >> 6, n = i & 63;
    float D = 0.f;
    if (n < 62){
      if (l == 0) D = 1.f;
      else {
        const float* src = (l == 1) ? Ls : A2s;
        for (int m = 0; m < 62; ++m) D += src[n*62 + m];
      }
    }
    dneg[i] = (D == 0.f) ? 0.f : 1.f / D;
  }
}

// ---------------- K1: weight transpose + bf16 convert ----------------
// WaT[lh][m 0..63][c 0..511] (m>=62 -> 0) ; WT[lh][o 0..63][c 0..511]
__global__ void k_prep_w(const float* __restrict__ Wa, const float* __restrict__ W,
                         unsigned short* __restrict__ WaT, unsigned short* __restrict__ WT)
{
  const int idx = blockIdx.x * 256 + threadIdx.x;
  if (idx < 786432){
    const int c = idx & 511, m = (idx >> 9) & 63, lh = idx >> 15;
    const float v = (m < 62) ? Wa[((size_t)lh*512 + c)*62 + m] : 0.f;
    WaT[idx] = f2bf(v);
  } else if (idx < 1572864){
    const int j = idx - 786432;
    const int c = j & 511, o = (j >> 9) & 63, lh = j >> 15;
    WT[j] = f2bf(W[((size_t)lh*512 + c)*64 + o]);
  }
}

// ---------------- main fused kernel: one block per batch element b ----------------
#define LP 72   // padded LDS leading dim (halfs): 144 B row stride -> 2-way banks only

__global__ __launch_bounds__(256, 2)
void k_main(const float* __restrict__ x,
            const unsigned short* __restrict__ WaT,
            const unsigned short* __restrict__ WT,
            const unsigned short* __restrict__ ahat,
            const float* __restrict__ dneg,
            float* __restrict__ out)
{
  // 32 KiB union:
  //   GEMM phase : chunk double-buffer buf[2], each 8192 halfs (Wa rows [0:4096), W rows [4096:8192))
  //   post phase : s_a / s_xwT / s_axwT (temporally disjoint, barrier-guarded)
  __shared__ __align__(16) unsigned short s_u[16384];
  __shared__ __align__(16) float s_dneg[192];
  __shared__ __align__(16) float s_red[256];
  __shared__ __align__(16) float s_red2[256];

  unsigned short* const s_a    = s_u;           // 64*LP = 4608 halfs
  unsigned short* const s_xwT  = s_u + 4608;    // 4608 halfs
  unsigned short* const s_axwT = s_u + 9216;    // 4608 halfs (ends 13824 < 16384)

  const int tid  = threadIdx.x;
  const int wv   = tid >> 6;      // wave 0..3
  const int lane = tid & 63;
  const int q    = lane >> 4;     // quad 0..3
  const int m15  = lane & 15;
  const int b    = blockIdx.x;
  const int r0   = 16*wv + 4*q;   // C/D-layout row base for this thread

  if (tid < 192) s_dneg[tid] = dneg[tid];

  // Staging geometry (per chunk kc: 64 rows x 64 halfs x 2 matrices = 16 KiB, 4 async16/thread).
  // Thread (s,wv,lane): row n = (s&1)*32 + wv*8 + (lane>>3); 16B slot p = lane&7 holds
  // global k-segment p ^ (n&7)  (XOR swizzle; n&7 == lane>>3 here).
  const int srow = lane >> 3;               // 0..7
  const int sseg = (lane & 7) ^ srow;       // pre-swizzled global segment

  // Persistent A-fragments: x[b] row (16*wv + m15), k = 32*kk + 8*q + j
  s16x8 afr[16];
  {
    const int row = 16*wv + m15;
    if (row < 62){
      const float* xp = x + ((size_t)b*62 + row)*512 + q*8;
      #pragma unroll
      for (int kk = 0; kk < 16; ++kk){
        const f32x4 f0 = *(const f32x4*)(xp + kk*32);
        const f32x4 f1 = *(const f32x4*)(xp + kk*32 + 4);
        s16x8 t;
        t[0]=(short)f2bf(f0[0]); t[1]=(short)f2bf(f0[1]); t[2]=(short)f2bf(f0[2]); t[3]=(short)f2bf(f0[3]);
        t[4]=(short)f2bf(f1[0]); t[5]=(short)f2bf(f1[1]); t[6]=(short)f2bf(f1[2]); t[7]=(short)f2bf(f1[3]);
        afr[kk] = t;
      }
    } else {
      #pragma unroll
      for (int kk = 0; kk < 16; ++kk){
        s16x8 t; t[0]=0;t[1]=0;t[2]=0;t[3]=0;t[4]=0;t[5]=0;t[6]=0;t[7]=0; afr[kk] = t;
      }
    }
  }

  #pragma unroll 1
  for (int h = 0; h < 8; ++h){
    f32x4 out_acc[4];
    #pragma unroll
    for (int ct = 0; ct < 4; ++ct) out_acc[ct] = zf4();

    #pragma unroll 1
    for (int l = 0; l < 3; ++l){
      const int lh = l*8 + h;
      const unsigned short* wa_base = WaT + (size_t)lh*32768;
      const unsigned short* wt_base = WT  + (size_t)lh*32768;

      // Stage one 16KiB chunk (both matrices) for K-window [kc*64, kc*64+64) into buf[bufsel].
      auto STAGE = [&](int kc, int bufsel){
        unsigned short* const lb = s_u + bufsel*8192;
        #pragma unroll
        for (int s = 0; s < 4; ++s){
          const int n = (s & 1)*32 + wv*8 + srow;
          const unsigned short* gb = (s < 2) ? wa_base : wt_base;
          const int loff = ((s < 2) ? 0 : 4096) + (s & 1)*2048 + wv*512 + lane*8;
          async16(gb + (size_t)n*512 + kc*64 + sseg*8, lb + loff);
        }
      };

      // ---- fused dual GEMM over K=512: logits = x@Wa, xW = x@W ----
      f32x4 accL[4], accX[4];
      #pragma unroll
      for (int ct = 0; ct < 4; ++ct){ accL[ct] = zf4(); accX[ct] = zf4(); }

      __syncthreads();                    // union handoff: prev phase readers done
      STAGE(0, 0);
      asm volatile("s_waitcnt vmcnt(0)" ::: "memory");
      __builtin_amdgcn_s_barrier();       // buf0 staged & visible
      __builtin_amdgcn_sched_barrier(0);

      #pragma unroll
      for (int kc = 0; kc < 8; ++kc){
        if (kc < 7) STAGE(kc + 1, (kc + 1) & 1);   // prefetch next chunk (other buffer)
        const unsigned short* bw = s_u + (kc & 1)*8192;
        #pragma unroll
        for (int ks = 0; ks < 2; ++ks){
          const s16x8 a = afr[kc*2 + ks];
          #pragma unroll
          for (int ct = 0; ct < 4; ++ct){
            const int off = (16*ct + m15)*64 + (((4*ks + q) ^ (m15 & 7)) * 8);
            const s16x8 bL = *(const s16x8*)(bw + off);
            const s16x8 bX = *(const s16x8*)(bw + 4096 + off);
            accL[ct] = __builtin_amdgcn_mfma_f32_16x16x32_bf16(a, bL, accL[ct], 0, 0, 0);
            accX[ct] = __builtin_amdgcn_mfma_f32_16x16x32_bf16(a, bX, accX[ct], 0, 0, 0);
          }
        }
        __builtin_amdgcn_sched_barrier(0);            // nothing crosses the sync
        asm volatile("s_waitcnt vmcnt(0)" ::: "memory"); // own prefetch landed
        __builtin_amdgcn_s_barrier();                 // all waves: cur read done, nxt staged
        __builtin_amdgcn_sched_barrier(0);
      }

      // ---- epilogue: scale by d_neg[n], leaky-relu, mask pad rows; stash xW^T ----
      {
        const f32x4 dn = *(const f32x4*)(&s_dneg[l*64 + r0]);
        #pragma unroll
        for (int ct = 0; ct < 4; ++ct){
          const int col = 16*ct + m15;
          #pragma unroll
          for (int r = 0; r < 4; ++r){
            const int n = r0 + r;
            float v = accL[ct][r] * dn[r];
            v = (v > 0.f) ? v : 0.01f*v;
            if (n >= 62) v = -1e30f;               // exclude pad rows from softmax
            s_a[n*LP + col]   = f2bf(v);
            s_xwT[col*LP + n] = f2bf(accX[ct][r]); // xwT[o][m']
          }
        }
      }
      __syncthreads();   // (A)

      // ---- axW = A_hat @ xW  (A-frags straight from global; L2-hot) ----
      f32x4 accA[4];
      #pragma unroll
      for (int ct = 0; ct < 4; ++ct) accA[ct] = zf4();
      #pragma unroll
      for (int ks = 0; ks < 2; ++ks){
        const s16x8 aA = *(const s16x8*)(ahat + (size_t)(l*64 + 16*wv + m15)*64 + ks*32 + q*8);
        #pragma unroll
        for (int ct = 0; ct < 4; ++ct){
          const s16x8 bA = *(const s16x8*)(&s_xwT[(16*ct + m15)*LP + ks*32 + q*8]);
          accA[ct] = __builtin_amdgcn_mfma_f32_16x16x32_bf16(aA, bA, accA[ct], 0, 0, 0);
        }
      }
      #pragma unroll
      for (int ct = 0; ct < 4; ++ct){
        #pragma unroll
        for (int r = 0; r < 4; ++r)
          s_axwT[(16*ct + m15)*LP + (r0 + r)] = f2bf(accA[ct][r]);  // axwT[o][m]
      }

      // ---- softmax over n: thread owns col=lane, rows 16*wv..16*wv+15 ----
      float vsm[16];
      float mp = -3.0e38f;
      #pragma unroll
      for (int i = 0; i < 16; ++i){
        vsm[i] = bf2f(s_a[(16*wv + i)*LP + lane]);
        mp = fmaxf(mp, vsm[i]);
      }
      s_red[wv*64 + lane] = mp;
      __syncthreads();   // (B)
      const float mc = fmaxf(fmaxf(s_red[lane], s_red[64 + lane]),
                             fmaxf(s_red[128 + lane], s_red[192 + lane]));
      float ev[16]; float sp = 0.f;
      #pragma unroll
      for (int i = 0; i < 16; ++i){ ev[i] = __expf(vsm[i] - mc); sp += ev[i]; }
      s_red2[wv*64 + lane] = sp;
      __syncthreads();   // (C)
      const float sc = s_red2[lane] + s_red2[64 + lane] + s_red2[128 + lane] + s_red2[192 + lane];
      const float inv = 1.0f / sc;
      #pragma unroll
      for (int i = 0; i < 16; ++i)
        s_a[(16*wv + i)*LP + lane] = f2bf(ev[i] * inv);
      __syncthreads();   // (D)

      // ---- o2 = a @ axW ; relu ; accumulate over layers ----
      f32x4 accO[4];
      #pragma unroll
      for (int ct = 0; ct < 4; ++ct) accO[ct] = zf4();
      #pragma unroll
      for (int ks = 0; ks < 2; ++ks){
        const s16x8 aO = *(const s16x8*)(&s_a[(16*wv + m15)*LP + ks*32 + q*8]);
        #pragma unroll
        for (int ct = 0; ct < 4; ++ct){
          const s16x8 bO = *(const s16x8*)(&s_axwT[(16*ct + m15)*LP + ks*32 + q*8]);
          accO[ct] = __builtin_amdgcn_mfma_f32_16x16x32_bf16(aO, bO, accO[ct], 0, 0, 0);
        }
      }
      #pragma unroll
      for (int ct = 0; ct < 4; ++ct){
        #pragma unroll
        for (int r = 0; r < 4; ++r)
          out_acc[ct][r] += fmaxf(accO[ct][r], 0.f);
      }
    } // l

    // ---- write this head's 64-wide output slice (final relu is a no-op on sum of relus) ----
    #pragma unroll
    for (int ct = 0; ct < 4; ++ct){
      const int col = h*64 + 16*ct + m15;
      #pragma unroll
      for (int r = 0; r < 4; ++r){
        const int n = r0 + r;
        if (n < 62)
          out[((size_t)b*62 + n)*512 + col] = fmaxf(out_acc[ct][r], 0.f);
      }
    }
  } // h
}

extern "C" void kernel_launch(void* const* d_in, const int* in_sizes, int n_in,
                              void* d_out, int out_size, void* d_ws, size_t ws_size,
                              hipStream_t stream)
{
  const float* x  = (const float*)d_in[0];   // (2048, 62, 512)
  const float* L  = (const float*)d_in[1];   // (62, 62)
  const float* Wa = (const float*)d_in[2];   // (3, 8, 512, 62)
  const float* W  = (const float*)d_in[3];   // (3, 8, 512, 64)
  float* out = (float*)d_out;                // (2048, 62, 512)

  char* ws = (char*)d_ws;
  unsigned short* ws_ahat = (unsigned short*)(ws);                   // 24576 B
  float*          ws_dneg = (float*)(ws + 24576);                    // 768 B
  unsigned short* ws_WaT  = (unsigned short*)(ws + 25600);           // 1572864 B
  unsigned short* ws_WT   = (unsigned short*)(ws + 25600 + 1572864); // 1572864 B

  k_prep_adj<<<1, 256, 0, stream>>>(L, ws_ahat, ws_dneg);
  k_prep_w<<<6144, 256, 0, stream>>>(Wa, W, ws_WaT, ws_WT);
  k_main<<<2048, 256, 0, stream>>>(x, ws_WaT, ws_WT, ws_ahat, ws_dneg, out);
}

// Round 5
// 1007.187 us; speedup vs baseline: 1.2366x; 1.2366x over previous
//
#include <hip/hip_runtime.h>

// Problem constants: B=2048, N=62 (pad 64), C_IN=512, L=3 layers, H=8, O=64.
// Round-1 proven structure (256 thr/block, 32KB LDS union, 4 kc x K=128 staging)
// + softmax simplification: no max-subtraction (range-safe), 1/S folded into
// axW rows at write time -> 2 fewer barriers + ~60 VALU per (l,h).

using f32x4 = __attribute__((ext_vector_type(4))) float;
using s16x8 = __attribute__((ext_vector_type(8))) short;

__device__ __forceinline__ unsigned short f2bf(float f){
  unsigned int u = __builtin_bit_cast(unsigned int, f);
  u += 0x7fffu + ((u >> 16) & 1u);              // RNE
  return (unsigned short)(u >> 16);
}
__device__ __forceinline__ float bf2f(unsigned short h){
  unsigned int u = ((unsigned int)h) << 16;
  return __builtin_bit_cast(float, u);
}
__device__ __forceinline__ f32x4 zf4(){ f32x4 v; v[0]=0.f; v[1]=0.f; v[2]=0.f; v[3]=0.f; return v; }

__device__ __forceinline__ unsigned long long pack4bf(float a, float b, float c, float d){
  return (unsigned long long)f2bf(a)
       | ((unsigned long long)f2bf(b) << 16)
       | ((unsigned long long)f2bf(c) << 32)
       | ((unsigned long long)f2bf(d) << 48);
}

__device__ __forceinline__ void async16(const void* g, void* l){
  __builtin_amdgcn_global_load_lds((const __attribute__((address_space(1))) unsigned int*)g,
                                   (__attribute__((address_space(3))) unsigned int*)l,
                                   16, 0, 0);
}

// ---------------- K0: adjacency powers, A_hat (bf16, zero-padded 64x64), d_neg ----------------
__global__ void k_prep_adj(const float* __restrict__ L,
                           unsigned short* __restrict__ ahat,  // [3][64][64] bf16
                           float* __restrict__ dneg)           // [3][64] f32
{
  __shared__ float Ls[62*62];
  __shared__ float A2s[62*62];
  const int tid = threadIdx.x;
  const int NT  = blockDim.x;
  for (int i = tid; i < 62*62; i += NT) Ls[i] = L[i];
  __syncthreads();
  for (int i = tid; i < 62*62; i += NT){
    const int n = i / 62, m = i % 62;
    float s = 0.f;
    for (int k = 0; k < 62; ++k) s += Ls[n*62 + k] * Ls[k*62 + m];
    A2s[i] = s;
  }
  __syncthreads();
  for (int i = tid; i < 3*64*64; i += NT){
    const int l = i >> 12, r = i & 4095, n = r >> 6, m = r & 63;
    float v = 0.f;
    if (n < 62 && m < 62){
      float base = 0.f;
      if (l == 0) base = (n == m) ? 1.f : 0.f;
      else if (l == 1) base = Ls[n*62 + m];
      else base = A2s[n*62 + m];
      v = base + ((n == m) ? 1.f : 0.f);          // A_hat = A + I
    }
    ahat[i] = f2bf(v);
  }
  for (int i = tid; i < 3*64; i += NT){
    const int l = i >> 6, n = i & 63;
    float D = 0.f;
    if (n < 62){
      if (l == 0) D = 1.f;
      else {
        const float* src = (l == 1) ? Ls : A2s;
        for (int m = 0; m < 62; ++m) D += src[n*62 + m];
      }
    }
    dneg[i] = (D == 0.f) ? 0.f : 1.f / D;
  }
}

// ---------------- K1: weight transpose + bf16 convert ----------------
// WaT[lh][m 0..63][c 0..511] (m>=62 -> 0) ; WT[lh][o 0..63][c 0..511]
__global__ void k_prep_w(const float* __restrict__ Wa, const float* __restrict__ W,
                         unsigned short* __restrict__ WaT, unsigned short* __restrict__ WT)
{
  const int idx = blockIdx.x * 256 + threadIdx.x;
  if (idx < 786432){
    const int c = idx & 511, m = (idx >> 9) & 63, lh = idx >> 15;
    const float v = (m < 62) ? Wa[((size_t)lh*512 + c)*62 + m] : 0.f;
    WaT[idx] = f2bf(v);
  } else if (idx < 1572864){
    const int j = idx - 786432;
    const int c = j & 511, o = (j >> 9) & 63, lh = j >> 15;
    WT[j] = f2bf(W[((size_t)lh*512 + c)*64 + o]);
  }
}

// ---------------- main fused kernel: one block per batch element b ----------------
#define LP 72   // padded LDS leading dim (halfs): 144 B row stride -> 2-way banks only

__global__ __launch_bounds__(256, 2)
void k_main(const float* __restrict__ x,
            const unsigned short* __restrict__ WaT,
            const unsigned short* __restrict__ WT,
            const unsigned short* __restrict__ ahat,
            const float* __restrict__ dneg,
            float* __restrict__ out)
{
  // 32 KiB union: during the dual GEMM it is s_chunk[2][8192];
  // afterwards it is s_a / s_xwT / s_axwT (temporally disjoint, barrier-guarded).
  __shared__ __align__(16) unsigned short s_u[16384];
  __shared__ __align__(16) float s_dneg[192];
  __shared__ __align__(16) float s_red[256];

  unsigned short* const s_chunk0 = s_u;           // 8192 halfs (Wa chunk)
  unsigned short* const s_chunk1 = s_u + 8192;    // 8192 halfs (W chunk)
  unsigned short* const s_a      = s_u;           // 64*LP = 4608 halfs (holds ev)
  unsigned short* const s_xwT    = s_u + 4608;    // 4608 halfs
  unsigned short* const s_axwT   = s_u + 9216;    // 4608 halfs (ends 13824 < 16384)

  const int tid  = threadIdx.x;
  const int wv   = tid >> 6;      // wave 0..3
  const int lane = tid & 63;
  const int q    = lane >> 4;     // quad 0..3
  const int m15  = lane & 15;
  const int b    = blockIdx.x;
  const int r0   = 16*wv + 4*q;   // C/D-layout row base for this thread

  if (tid < 192) s_dneg[tid] = dneg[tid];

  // Persistent A-fragments: x[b] row (16*wv + m15), k = 32*kk + 8*q + j
  s16x8 afr[16];
  {
    const int row = 16*wv + m15;
    if (row < 62){
      const float* xp = x + ((size_t)b*62 + row)*512 + q*8;
      #pragma unroll
      for (int kk = 0; kk < 16; ++kk){
        const f32x4 f0 = *(const f32x4*)(xp + kk*32);
        const f32x4 f1 = *(const f32x4*)(xp + kk*32 + 4);
        s16x8 t;
        t[0]=(short)f2bf(f0[0]); t[1]=(short)f2bf(f0[1]); t[2]=(short)f2bf(f0[2]); t[3]=(short)f2bf(f0[3]);
        t[4]=(short)f2bf(f1[0]); t[5]=(short)f2bf(f1[1]); t[6]=(short)f2bf(f1[2]); t[7]=(short)f2bf(f1[3]);
        afr[kk] = t;
      }
    } else {
      #pragma unroll
      for (int kk = 0; kk < 16; ++kk){
        s16x8 t; t[0]=0;t[1]=0;t[2]=0;t[3]=0;t[4]=0;t[5]=0;t[6]=0;t[7]=0; afr[kk] = t;
      }
    }
  }

  #pragma unroll 1
  for (int h = 0; h < 8; ++h){
    f32x4 out_acc[4];
    #pragma unroll
    for (int ct = 0; ct < 4; ++ct) out_acc[ct] = zf4();

    #pragma unroll 1
    for (int l = 0; l < 3; ++l){
      const int lh = l*8 + h;
      const unsigned short* wa_base = WaT + (size_t)lh*32768;
      const unsigned short* wt_base = WT  + (size_t)lh*32768;

      // ---- fused dual GEMM over K=512: logits = x@Wa, xW = x@W ----
      f32x4 accL[4], accX[4];
      #pragma unroll
      for (int ct = 0; ct < 4; ++ct){ accL[ct] = zf4(); accX[ct] = zf4(); }

      #pragma unroll
      for (int kc = 0; kc < 4; ++kc){
        __syncthreads();  // protect s_u from previous readers (chunk or o2)
        #pragma unroll
        for (int tt = 0; tt < 4; ++tt){
          const int n  = 16*tt + 4*wv + q;         // weight row (logical)
          const int jl = m15 ^ (n & 15);           // XOR-swizzled 16B block gather
          const size_t goff = (size_t)n*512 + (size_t)kc*128 + (size_t)jl*8;
          const int    loff = tt*2048 + wv*512 + lane*8;  // contiguous per-wave LDS dest
          async16(wa_base + goff, s_chunk0 + loff);
          async16(wt_base + goff, s_chunk1 + loff);
        }
        __syncthreads();  // drains vmcnt -> chunk visible
        #pragma unroll
        for (int ks = 0; ks < 4; ++ks){
          const s16x8 a = afr[kc*4 + ks];
          #pragma unroll
          for (int ct = 0; ct < 4; ++ct){
            const int off = (16*ct + m15)*128 + (((4*ks + q) ^ m15) * 8);
            const s16x8 bL = *(const s16x8*)(s_chunk0 + off);
            const s16x8 bX = *(const s16x8*)(s_chunk1 + off);
            accL[ct] = __builtin_amdgcn_mfma_f32_16x16x32_bf16(a, bL, accL[ct], 0, 0, 0);
            accX[ct] = __builtin_amdgcn_mfma_f32_16x16x32_bf16(a, bX, accX[ct], 0, 0, 0);
          }
        }
      }
      __syncthreads();  // all waves done reading s_chunk before union overwrite

      // ---- epilogue: ev = exp(leaky(d_neg*logit)) (no max-sub; range <= e^8), pad rows -> 0;
      //      stash xW^T (packed b64 writes, n-contiguous) ----
      {
        const f32x4 dn = *(const f32x4*)(&s_dneg[l*64 + r0]);
        #pragma unroll
        for (int ct = 0; ct < 4; ++ct){
          const int col = 16*ct + m15;
          *(unsigned long long*)(&s_xwT[col*LP + r0]) =
              pack4bf(accX[ct][0], accX[ct][1], accX[ct][2], accX[ct][3]);  // xwT[o][m']
          #pragma unroll
          for (int r = 0; r < 4; ++r){
            const int n = r0 + r;
            float v = accL[ct][r] * dn[r];
            v = (v > 0.f) ? v : 0.01f*v;
            const float e = (n < 62) ? __expf(v) : 0.f;   // pad rows contribute 0
            s_a[n*LP + col] = f2bf(e);
          }
        }
      }
      __syncthreads();   // (A)

      // ---- column sums S[m] = sum_n ev[n,m]: thread owns col=lane, rows 16*wv..+15 ----
      {
        float sp = 0.f;
        #pragma unroll
        for (int i = 0; i < 16; ++i)
          sp += bf2f(s_a[(16*wv + i)*LP + lane]);
        s_red[wv*64 + lane] = sp;
      }

      // ---- axW = A_hat @ xW  (A-frags straight from global; L2-hot) ----
      f32x4 accA[4];
      #pragma unroll
      for (int ct = 0; ct < 4; ++ct) accA[ct] = zf4();
      #pragma unroll
      for (int ks = 0; ks < 2; ++ks){
        const s16x8 aA = *(const s16x8*)(ahat + (size_t)(l*64 + 16*wv + m15)*64 + ks*32 + q*8);
        #pragma unroll
        for (int ct = 0; ct < 4; ++ct){
          const s16x8 bA = *(const s16x8*)(&s_xwT[(16*ct + m15)*LP + ks*32 + q*8]);
          accA[ct] = __builtin_amdgcn_mfma_f32_16x16x32_bf16(aA, bA, accA[ct], 0, 0, 0);
        }
      }
      __syncthreads();   // (C) s_red complete

      // ---- write axW^T scaled by 1/S[m]  (folds softmax denominator; packed b64) ----
      {
        f32x4 inv4;
        #pragma unroll
        for (int r = 0; r < 4; ++r){
          const int m = r0 + r;
          const float S = s_red[m] + s_red[64 + m] + s_red[128 + m] + s_red[192 + m];
          inv4[r] = 1.0f / S;
        }
        #pragma unroll
        for (int ct = 0; ct < 4; ++ct){
          *(unsigned long long*)(&s_axwT[(16*ct + m15)*LP + r0]) =
              pack4bf(accA[ct][0]*inv4[0], accA[ct][1]*inv4[1],
                      accA[ct][2]*inv4[2], accA[ct][3]*inv4[3]);   // axwT[o][m] * invS[m]
        }
      }
      __syncthreads();   // (D)

      // ---- o2 = ev @ (axW/S) ; relu ; accumulate over layers ----
      f32x4 accO[4];
      #pragma unroll
      for (int ct = 0; ct < 4; ++ct) accO[ct] = zf4();
      #pragma unroll
      for (int ks = 0; ks < 2; ++ks){
        const s16x8 aO = *(const s16x8*)(&s_a[(16*wv + m15)*LP + ks*32 + q*8]);
        #pragma unroll
        for (int ct = 0; ct < 4; ++ct){
          const s16x8 bO = *(const s16x8*)(&s_axwT[(16*ct + m15)*LP + ks*32 + q*8]);
          accO[ct] = __builtin_amdgcn_mfma_f32_16x16x32_bf16(aO, bO, accO[ct], 0, 0, 0);
        }
      }
      #pragma unroll
      for (int ct = 0; ct < 4; ++ct){
        #pragma unroll
        for (int r = 0; r < 4; ++r)
          out_acc[ct][r] += fmaxf(accO[ct][r], 0.f);
      }
    } // l

    // ---- write this head's 64-wide output slice (final relu is a no-op on sum of relus) ----
    #pragma unroll
    for (int ct = 0; ct < 4; ++ct){
      const int col = h*64 + 16*ct + m15;
      #pragma unroll
      for (int r = 0; r < 4; ++r){
        const int n = r0 + r;
        if (n < 62)
          out[((size_t)b*62 + n)*512 + col] = fmaxf(out_acc[ct][r], 0.f);
      }
    }
  } // h
}

extern "C" void kernel_launch(void* const* d_in, const int* in_sizes, int n_in,
                              void* d_out, int out_size, void* d_ws, size_t ws_size,
                              hipStream_t stream)
{
  const float* x  = (const float*)d_in[0];   // (2048, 62, 512)
  const float* L  = (const float*)d_in[1];   // (62, 62)
  const float* Wa = (const float*)d_in[2];   // (3, 8, 512, 62)
  const float* W  = (const float*)d_in[3];   // (3, 8, 512, 64)
  float* out = (float*)d_out;                // (2048, 62, 512)

  char* ws = (char*)d_ws;
  unsigned short* ws_ahat = (unsigned short*)(ws);                   // 24576 B
  float*          ws_dneg = (float*)(ws + 24576);                    // 768 B
  unsigned short* ws_WaT  = (unsigned short*)(ws + 25600);           // 1572864 B
  unsigned short* ws_WT   = (unsigned short*)(ws + 25600 + 1572864); // 1572864 B

  k_prep_adj<<<1, 1024, 0, stream>>>(L, ws_ahat, ws_dneg);
  k_prep_w<<<6144, 256, 0, stream>>>(Wa, W, ws_WaT, ws_WT);
  k_main<<<2048, 256, 0, stream>>>(x, ws_WaT, ws_WT, ws_ahat, ws_dneg, out);
}